// Round 7
// baseline (436.233 us; speedup 1.0000x reference)
//
#include <hip/hip_runtime.h>
#include <math.h>

typedef unsigned short u16;
typedef __attribute__((ext_vector_type(8))) __bf16 bf16x8;
typedef __attribute__((ext_vector_type(4))) float f32x4;
typedef __attribute__((ext_vector_type(4))) u16 u16x4;
typedef __attribute__((ext_vector_type(8))) u16 u16x8;
typedef __attribute__((ext_vector_type(4))) float float4v;

constexpr int kS = 1024;
constexpr int kD = 1024;
constexpr int kDinner = 2048;
constexpr int kHeads = 32;
constexpr int kConvDim = 2176;
constexpr int kDproj = 4256;
constexpr int kDprojPad = 4352;
constexpr int kRows = 2048;   // B*S
constexpr int kHmlp = 8192;
constexpr int kHhalf = 4096;
constexpr int kL = 64;        // scan chunk length
constexpr int kNC = 16;       // chunks per sequence

__device__ __forceinline__ float bf2f(u16 u) {
    return __builtin_bit_cast(float, (unsigned int)u << 16);
}
__device__ __forceinline__ u16 f2bf(float f) {
    unsigned int u = __builtin_bit_cast(unsigned int, f);
    u += 0x7fffu + ((u >> 16) & 1u);
    return (u16)(u >> 16);
}
__device__ __forceinline__ float silu_(float x) { return x / (1.f + __expf(-x)); }

// async global->LDS, 16B per lane; LDS dest = wave-uniform base + lane*16
__device__ __forceinline__ void gld16(const u16* g, u16* l) {
    __builtin_amdgcn_global_load_lds(
        (const __attribute__((address_space(1))) void*)g,
        (__attribute__((address_space(3))) void*)l, 16, 0, 0);
}

// ---------------- fused casts: all 5 fp32->bf16 conversions in one launch ----
// fc1 is row-PERMUTED on cast so the MLP gate pair (a_p, g_p) lands in columns
// c and c+16 of the SAME lane's accumulator blocks:
//   a-row p      -> col (p>>4)*32 + (p&15)
//   g-row 4096+p -> col (p>>4)*32 + (p&15) + 16
constexpr int kB1 = kRows * kD / 4;                       // x
constexpr int kB2 = kB1 + kDprojPad * kD / 4;             // in_proj (padded)
constexpr int kB3 = kB2 + kD * kDinner / 4;               // out_proj
constexpr int kB4 = kB3 + kHmlp * kD / 4;                 // fc1 (permuted)
constexpr int kB5 = kB4 + kD * kHhalf / 4;                // fc2
__global__ __launch_bounds__(256)
void cast_all_kernel(const float* __restrict__ x, const float* __restrict__ w1,
                     const float* __restrict__ w2, const float* __restrict__ w3,
                     const float* __restrict__ w4, u16* __restrict__ xbf,
                     u16* __restrict__ w1bf, u16* __restrict__ w2bf,
                     u16* __restrict__ w3bf, u16* __restrict__ w4bf) {
    int i = blockIdx.x * 256 + threadIdx.x;
    const float* src;
    u16* dst;
    int j;
    if (i < kB1) {
        j = i; src = x; dst = xbf;
    } else if (i < kB2) {
        j = i - kB1;
        int e = j * 4, row = e >> 10, col = e & 1023;
        u16x4 o = {0, 0, 0, 0};
        if (row < kDproj) {
            float4v v = *(const float4v*)(w1 + (size_t)row * kD + col);
            o.x = f2bf(v.x); o.y = f2bf(v.y); o.z = f2bf(v.z); o.w = f2bf(v.w);
        }
        ((u16x4*)w1bf)[j] = o;
        return;
    } else if (i < kB3) {
        j = i - kB2; src = w2; dst = w2bf;
    } else if (i < kB4) {
        j = i - kB3;
        int e = j * 4, row = e >> 10, col4 = (e & 1023) >> 2;
        int p = (row < kHhalf) ? row : row - kHhalf;
        int permrow = (p >> 4) * 32 + (p & 15) + ((row < kHhalf) ? 0 : 16);
        float4v v = ((const float4v*)w3)[j];
        u16x4 o;
        o.x = f2bf(v.x); o.y = f2bf(v.y); o.z = f2bf(v.z); o.w = f2bf(v.w);
        ((u16x4*)w3bf)[permrow * 256 + col4] = o;
        return;
    } else {
        j = i - kB4; src = w4; dst = w4bf;
    }
    float4v v = ((const float4v*)src)[j];
    u16x4 o;
    o.x = f2bf(v.x); o.y = f2bf(v.y); o.z = f2bf(v.z); o.w = f2bf(v.w);
    ((u16x4*)dst)[j] = o;
}

// ---------------- GEMM: C[M,N] = A[M,K] * W[N,K]^T ----------------
// m97 staging + double-buffered LDS, one barrier per K-iter.
// LDS layout is kc-major within each 16-row block: staging lane l loads
// (row = l&15, kchunk = l>>4) so the MFMA fragment read is block_base +
// lane*16B -> perfectly sequential ds_read_b128, ZERO bank conflicts
// (previous row-major layout had 8-way conflicts; 4.19M/dispatch).
// blockIdx.z = split-K slice (partials at Cout + z*M*N, fp32, no resid).
// GATED: W is the permuted fc1; gate pair sits in ni blocks (2p, 2p+1) of the
// same lane -> epilogue computes a*silu(g) with no shuffle, all lanes store.
template <bool OUT_BF16, bool GATED = false>
__global__ __launch_bounds__(256)
void gemm_bt(const u16* __restrict__ A, const u16* __restrict__ W,
             void* __restrict__ Cout, const float* __restrict__ resid,
             int M, int N, int K) {
    __shared__ u16 As[2][128 * 32];
    __shared__ u16 Bs[2][128 * 32];
    const int tid = threadIdx.x;
    const int lane = tid & 63;
    const int w = __builtin_amdgcn_readfirstlane(tid >> 6);
    const int wm = w >> 1, wn = w & 1;
    const int bm = blockIdx.y * 128;
    const int bn = blockIdx.x * 128;
    const int z = blockIdx.z;
    const int Kchunk = K / gridDim.z;
    const int k0 = z * Kchunk;

    f32x4 acc[4][4];
#pragma unroll
    for (int i = 0; i < 4; i++)
#pragma unroll
        for (int j = 0; j < 4; j++) acc[i][j] = {0.f, 0.f, 0.f, 0.f};

    // staging: lane -> (row = lane&15, kchunk = lane>>4); LDS dest lane*16B
    const int srow = lane & 15;
    const int scol = (lane >> 4) * 8;    // k elem
    const u16* gA = A + (size_t)(bm + w * 32 + srow) * K + k0 + scol;
    const u16* gB = W + (size_t)(bn + w * 32 + srow) * K + k0 + scol;
    const size_t rstep = (size_t)16 * K;

    const int sbase0 = (w * 32) * 32;
    const int sbase1 = (w * 32 + 16) * 32;

    // prologue: stage tile 0 into buffer 0
    gld16(gA, &As[0][sbase0]);
    gld16(gA + rstep, &As[0][sbase1]);
    gld16(gB, &Bs[0][sbase0]);
    gld16(gB + rstep, &Bs[0][sbase1]);

    const int nk = Kchunk >> 5;
    for (int i = 0; i < nk; i++) {
        const int cur = i & 1, nxt = cur ^ 1;
        __syncthreads();   // drains DMA for buf[cur]; buf[nxt] reads finished
        if (i + 1 < nk) {
            int kt2 = (i + 1) * 32;
            gld16(gA + kt2, &As[nxt][sbase0]);
            gld16(gA + kt2 + rstep, &As[nxt][sbase1]);
            gld16(gB + kt2, &Bs[nxt][sbase0]);
            gld16(gB + kt2 + rstep, &Bs[nxt][sbase1]);
        }
        bf16x8 av[4], bv[4];
#pragma unroll
        for (int mi = 0; mi < 4; mi++)
            av[mi] = *(const bf16x8*)&As[cur][(wm * 64 + mi * 16) * 32 + lane * 8];
#pragma unroll
        for (int ni = 0; ni < 4; ni++)
            bv[ni] = *(const bf16x8*)&Bs[cur][(wn * 64 + ni * 16) * 32 + lane * 8];
#pragma unroll
        for (int mi = 0; mi < 4; mi++)
#pragma unroll
            for (int ni = 0; ni < 4; ni++)
                acc[mi][ni] = __builtin_amdgcn_mfma_f32_16x16x32_bf16(av[mi], bv[ni], acc[mi][ni], 0, 0, 0);
    }

    const int rb = bm + wm * 64 + ((lane >> 4) << 2);
    const int cb = bn + wn * 64 + (lane & 15);
    if (GATED) {
        // ni pair (2p, 2p+1): a in block 2p, g in block 2p+1, same lane.
        // gate-col = (bn + wn*64)/2 + p*16 + (lane&15)
        u16* Cb = (u16*)Cout;
        const int NG = N >> 1;
        const int gc0 = ((bn + wn * 64) >> 1) + (lane & 15);
#pragma unroll
        for (int mi = 0; mi < 4; mi++) {
#pragma unroll
            for (int p = 0; p < 2; p++) {
#pragma unroll
                for (int r = 0; r < 4; r++) {
                    float a = acc[mi][2 * p][r];
                    float g = acc[mi][2 * p + 1][r];
                    Cb[(size_t)(rb + mi * 16 + r) * NG + gc0 + p * 16] =
                        f2bf(a * silu_(g));
                }
            }
        }
        return;
    }
    float* Cf = (float*)Cout + (size_t)z * M * N;
    u16* Cb = (u16*)Cout;
#pragma unroll
    for (int mi = 0; mi < 4; mi++) {
#pragma unroll
        for (int ni = 0; ni < 4; ni++) {
#pragma unroll
            for (int r = 0; r < 4; r++) {
                size_t offo = (size_t)(rb + mi * 16 + r) * N + (cb + ni * 16);
                float v = acc[mi][ni][r];
                if (resid) v += resid[offo];
                if (OUT_BF16) Cb[offo] = f2bf(v);
                else Cf[offo] = v;
            }
        }
    }
}

// ---------------- split-K reduce (SK=4) + residual, fp32 out ----------------
__global__ __launch_bounds__(256)
void splitk_reduce_kernel(const float* __restrict__ Cp, const float* __restrict__ resid,
                          float* __restrict__ out, int mn4) {
    int i = blockIdx.x * 256 + threadIdx.x;
    if (i >= mn4) return;
    constexpr size_t MN = (size_t)kRows * kD;
    float4v s0 = ((const float4v*)Cp)[i];
    float4v s1 = ((const float4v*)(Cp + MN))[i];
    float4v s2 = ((const float4v*)(Cp + 2 * MN))[i];
    float4v s3 = ((const float4v*)(Cp + 3 * MN))[i];
    float4v r = ((const float4v*)resid)[i];
    float4v o;
    o.x = s0.x + s1.x + s2.x + s3.x + r.x;
    o.y = s0.y + s1.y + s2.y + s3.y + r.y;
    o.z = s0.z + s1.z + s2.z + s3.z + r.z;
    o.w = s0.w + s1.w + s2.w + s3.w + r.w;
    ((float4v*)out)[i] = o;
}

// ------- fused: split-K reduce + residual + RMSNorm(1024) -> x2 fp32, xn bf16
__global__ __launch_bounds__(256)
void reduce_rms_kernel(const float* __restrict__ Cp, const float* __restrict__ resid,
                       float* __restrict__ x2, const float* __restrict__ rmsw,
                       u16* __restrict__ xnbf) {
    const int row = blockIdx.x;
    const int tid = threadIdx.x;
    constexpr size_t MN = (size_t)kRows * kD;
    size_t i = (size_t)row * (kD / 4) + tid;
    float4v s0 = ((const float4v*)Cp)[i];
    float4v s1 = ((const float4v*)(Cp + MN))[i];
    float4v s2 = ((const float4v*)(Cp + 2 * MN))[i];
    float4v s3 = ((const float4v*)(Cp + 3 * MN))[i];
    float4v r = ((const float4v*)resid)[i];
    float4v v;
    v.x = s0.x + s1.x + s2.x + s3.x + r.x;
    v.y = s0.y + s1.y + s2.y + s3.y + r.y;
    v.z = s0.z + s1.z + s2.z + s3.z + r.z;
    v.w = s0.w + s1.w + s2.w + s3.w + r.w;
    ((float4v*)x2)[i] = v;
    float ss = v.x * v.x + v.y * v.y + v.z * v.z + v.w * v.w;
#pragma unroll
    for (int off = 32; off > 0; off >>= 1) ss += __shfl_down(ss, off);
    __shared__ float red[4];
    int wv = tid >> 6, lane = tid & 63;
    if (lane == 0) red[wv] = ss;
    __syncthreads();
    ss = red[0] + red[1] + red[2] + red[3];
    float rstd = rsqrtf(ss * (1.f / kD) + 1e-5f);
    float4v wv4 = ((const float4v*)rmsw)[tid];
    u16x4 o;
    o.x = f2bf(v.x * rstd * wv4.x);
    o.y = f2bf(v.y * rstd * wv4.y);
    o.z = f2bf(v.z * rstd * wv4.z);
    o.w = f2bf(v.w * rstd * wv4.w);
    ((u16x4*)xnbf)[i] = o;
}

// ---------------- fused depthwise causal conv + silu + dt/dA ----------------
__global__ __launch_bounds__(256)
void convdt_kernel(const u16* __restrict__ zxbf, const float* __restrict__ convw,
                   const float* __restrict__ convb, u16* __restrict__ xsbf,
                   float* __restrict__ BCf, const float* __restrict__ dt_bias,
                   const float* __restrict__ A_log, float* __restrict__ dtf,
                   float* __restrict__ dAf) {
    int c = blockIdx.x * 256 + threadIdx.x;
    int row = blockIdx.y;                 // b*1024 + s
    if (c >= kConvDim + kHeads) return;
    if (c < kConvDim) {
        int s = row & (kS - 1);
        float acc = convb[c];
#pragma unroll
        for (int j = 0; j < 4; j++) {
            int sj = s - 3 + j;
            if (sj >= 0)
                acc += bf2f(zxbf[(size_t)(row - 3 + j) * kDprojPad + kDinner + c]) * convw[c * 4 + j];
        }
        float v = silu_(acc);
        if (c < kDinner) xsbf[(size_t)row * kDinner + c] = f2bf(v);
        else BCf[(size_t)row * 128 + (c - kDinner)] = v;
    } else {
        int h = c - kConvDim;
        float raw = bf2f(zxbf[(size_t)row * kDprojPad + (kDinner + kConvDim) + h]) + dt_bias[h];
        float dt = (raw > 20.f) ? raw : log1pf(__expf(raw));
        float dA = __expf(-dt * __expf(A_log[h]));
        dtf[(size_t)row * kHeads + h] = dt;
        dAf[(size_t)row * kHeads + h] = dA;
    }
}

// ---------------- Phase A: intra-chunk local scan ----------------
__global__ __launch_bounds__(256)
void scan_chunk_kernel(const u16* __restrict__ xsbf, const float* __restrict__ BCf,
                       const float* __restrict__ dtf, const float* __restrict__ dAf,
                       const float* __restrict__ Dv, u16* __restrict__ ysbf,
                       float* __restrict__ Pf, float* __restrict__ Scf) {
    const int c = blockIdx.x, h = blockIdx.y, b = blockIdx.z;
    const int tid = threadIdx.x;
    const int lane = tid & 63;
    const int nq = tid >> 6;
    const int p = nq * 16 + (lane & 15);
    const int ng = lane >> 4;

    __shared__ float BC_lds[kL * 136];   // B at t*136+n, C at t*136+68+n
    __shared__ u16 xs_lds[kL * 64];
    __shared__ float dA_lds[kL];
    __shared__ float dt_lds[kL];
    __shared__ u16 ybuf[kL * 64];

    const int row0 = b * kS + c * kL;

#pragma unroll
    for (int i = 0; i < 8; i++) {
        int e4 = i * 256 + tid;
        int t = e4 >> 5;
        int col = (e4 & 31) * 4;
        float4v v = *(const float4v*)(BCf + (size_t)(row0 + t) * 128 + col);
        int dst = t * 136 + (col < 64 ? col : col + 4);
        *(float4v*)&BC_lds[dst] = v;
    }
#pragma unroll
    for (int i = 0; i < 2; i++) {
        int e8 = i * 256 + tid;
        int t = e8 >> 3, col8 = (e8 & 7) * 8;
        *(u16x8*)&xs_lds[t * 64 + col8] =
            *(const u16x8*)(xsbf + (size_t)(row0 + t) * kDinner + h * 64 + col8);
    }
    if (tid < kL) {
        dt_lds[tid] = dtf[(size_t)(row0 + tid) * kHeads + h];
        dA_lds[tid] = dAf[(size_t)(row0 + tid) * kHeads + h];
    }
    __syncthreads();

    float hst[16];
#pragma unroll
    for (int j = 0; j < 16; j++) hst[j] = 0.f;
    float P = 1.f;
    const float Dh = Dv[h];

    for (int t = 0; t < kL; t++) {
        float dAv = dA_lds[t];
        float dtv = dt_lds[t];
        float xsv = bf2f(xs_lds[t * 64 + p]);
        float dtx = dtv * xsv;
        P *= dAv;
        const float* Bt = &BC_lds[t * 136 + ng * 16];
        const float* Ct = Bt + 68;
        float yp = 0.f;
#pragma unroll
        for (int j = 0; j < 16; j++) {
            float Bn = Bt[j];
            float Cn = Ct[j];
            hst[j] = hst[j] * dAv + dtx * Bn;
            yp += hst[j] * Cn;
        }
        yp += __shfl_xor(yp, 16);
        yp += __shfl_xor(yp, 32);
        if (ng == 0) ybuf[t * 64 + p] = f2bf(yp + Dh * xsv);
        if (tid == 0) Pf[(size_t)(row0 + t) * kHeads + h] = P;
    }
    __syncthreads();

#pragma unroll
    for (int i = 0; i < 2; i++) {
        int e8 = i * 256 + tid;
        int t = e8 >> 3, col8 = (e8 & 7) * 8;
        *(u16x8*)(ysbf + (size_t)(row0 + t) * kDinner + h * 64 + col8) =
            *(u16x8*)&ybuf[t * 64 + col8];
    }
    const int bhc = (b * 32 + h) * kNC + c;
    float* Sdst = Scf + (size_t)bhc * 4096 + p * 64 + ng * 16;
#pragma unroll
    for (int j = 0; j < 16; j += 4) {
        f32x4 v = {hst[j], hst[j + 1], hst[j + 2], hst[j + 3]};
        *(f32x4*)(Sdst + j) = v;
    }
}

// ---------------- Phase B: sequential chunk-state combine ----------------
__global__ __launch_bounds__(256)
void chunk_state_kernel(const float* __restrict__ Scf, const float* __restrict__ Pf,
                        float* __restrict__ Hinf) {
    const int bh = blockIdx.x;
    const int b = bh >> 5, h = bh & 31;
    const int tid = threadIdx.x;
    float hreg[16];
#pragma unroll
    for (int k = 0; k < 16; k++) hreg[k] = 0.f;
    for (int c = 0; c < kNC - 1; c++) {
        float Q = Pf[(size_t)(b * kS + c * kL + kL - 1) * kHeads + h];
        size_t sbase = (size_t)(bh * kNC + c) * 4096;
        size_t dbase = (size_t)(bh * kNC + c + 1) * 4096;
#pragma unroll
        for (int k = 0; k < 16; k++) {
            float s = Scf[sbase + k * 256 + tid];
            hreg[k] = Q * hreg[k] + s;
            Hinf[dbase + k * 256 + tid] = hreg[k];
        }
    }
}

// ---------------- Phase C: cross-chunk correction ----------------
__global__ __launch_bounds__(256)
void chunk_corr_kernel(const float* __restrict__ Hinf, const float* __restrict__ BCf,
                       const float* __restrict__ Pf, u16* __restrict__ ysbf) {
    const int c = blockIdx.x + 1;
    const int h = blockIdx.y, b = blockIdx.z;
    const int tid = threadIdx.x;
    const int lane = tid & 63, wq = tid >> 6;
    __shared__ float Hin_lds[64 * 65];
    __shared__ float C_lds[kL * 64];
    const int bh = b * 32 + h;
    const size_t hbase = (size_t)(bh * kNC + c) * 4096;
#pragma unroll
    for (int k = 0; k < 16; k++) {
        int e = k * 256 + tid;
        Hin_lds[(e >> 6) * 65 + (e & 63)] = Hinf[hbase + e];
    }
    const int row0 = b * kS + c * kL;
#pragma unroll
    for (int k = 0; k < 4; k++) {
        int e4 = k * 256 + tid;
        int t = e4 >> 4, n4 = (e4 & 15) * 4;
        *(float4v*)&C_lds[t * 64 + n4] =
            *(const float4v*)(BCf + (size_t)(row0 + t) * 128 + 64 + n4);
    }
    __syncthreads();

    float hr[64];
#pragma unroll
    for (int n = 0; n < 64; n++) hr[n] = Hin_lds[lane * 65 + n];

    for (int tt = 0; tt < 16; tt++) {
        int t = wq * 16 + tt;
        float corr = 0.f;
#pragma unroll
        for (int n4 = 0; n4 < 16; n4++) {
            float4v cv = *(const float4v*)&C_lds[t * 64 + n4 * 4];
            corr += cv.x * hr[n4 * 4] + cv.y * hr[n4 * 4 + 1] +
                    cv.z * hr[n4 * 4 + 2] + cv.w * hr[n4 * 4 + 3];
        }
        float Pt = Pf[(size_t)(row0 + t) * kHeads + h];
        size_t yoff = (size_t)(row0 + t) * kDinner + h * 64 + lane;
        ysbf[yoff] = f2bf(bf2f(ysbf[yoff]) + Pt * corr);
    }
}

// ---------------- gate (silu(z)) + rmsnorm over 2048 ----------------
__global__ __launch_bounds__(256)
void gatenorm_kernel(const u16* __restrict__ ysbf, const u16* __restrict__ zxbf,
                     const float* __restrict__ normw, u16* __restrict__ ybf) {
    const int row = blockIdx.x;
    const int tid = threadIdx.x;
    float v[8];
    float ss = 0.f;
#pragma unroll
    for (int i = 0; i < 8; i++) {
        int idx = i * 256 + tid;
        float y = bf2f(ysbf[(size_t)row * kDinner + idx]);
        float z = bf2f(zxbf[(size_t)row * kDprojPad + idx]);
        v[i] = y * silu_(z);
        ss += v[i] * v[i];
    }
#pragma unroll
    for (int off = 32; off > 0; off >>= 1) ss += __shfl_down(ss, off);
    __shared__ float red[4];
    int wv = tid >> 6, lane = tid & 63;
    if (lane == 0) red[wv] = ss;
    __syncthreads();
    ss = red[0] + red[1] + red[2] + red[3];
    float rstd = rsqrtf(ss * (1.f / kDinner) + 1e-5f);
#pragma unroll
    for (int i = 0; i < 8; i++) {
        int idx = i * 256 + tid;
        ybf[(size_t)row * kDinner + idx] = f2bf(v[i] * rstd * normw[idx]);
    }
}

extern "C" void kernel_launch(void* const* d_in, const int* in_sizes, int n_in,
                              void* d_out, int out_size, void* d_ws, size_t ws_size,
                              hipStream_t stream) {
    const float* x         = (const float*)d_in[0];
    const float* in_proj_w = (const float*)d_in[1];
    const float* conv_w    = (const float*)d_in[2];
    const float* conv_b    = (const float*)d_in[3];
    const float* dt_bias   = (const float*)d_in[4];
    const float* A_log     = (const float*)d_in[5];
    const float* Dvec      = (const float*)d_in[6];
    const float* ssm_norm_w= (const float*)d_in[7];
    const float* out_proj_w= (const float*)d_in[8];
    const float* rms_w     = (const float*)d_in[9];
    const float* fc1_w     = (const float*)d_in[10];
    const float* fc2_w     = (const float*)d_in[11];
    float* out = (float*)d_out;

    char* ws = (char*)d_ws;
    size_t off = 0;
    auto alloc = [&](size_t bytes) -> void* {
        void* p = ws + off;
        off += (bytes + 255) & ~(size_t)255;
        return p;
    };
    u16*   xbf  = (u16*)alloc((size_t)kRows * kD * 2);
    u16*   w1bf = (u16*)alloc((size_t)kDprojPad * kD * 2);
    u16*   w2bf = (u16*)alloc((size_t)kD * kDinner * 2);
    u16*   w3bf = (u16*)alloc((size_t)kHmlp * kD * 2);
    u16*   w4bf = (u16*)alloc((size_t)kD * kHhalf * 2);
    u16*   zxbf = (u16*)alloc((size_t)kRows * kDprojPad * 2);
    u16*   xsbf = (u16*)alloc((size_t)kRows * kDinner * 2);
    float* BCf  = (float*)alloc((size_t)kRows * 128 * 4);
    float* dtf  = (float*)alloc((size_t)kRows * kHeads * 4);
    float* dAf  = (float*)alloc((size_t)kRows * kHeads * 4);
    float* Pf   = (float*)alloc((size_t)kRows * kHeads * 4);
    u16*   ysbf = (u16*)alloc((size_t)kRows * kDinner * 2);
    u16*   ybf  = (u16*)alloc((size_t)kRows * kDinner * 2);
    float* x2   = (float*)alloc((size_t)kRows * kD * 4);
    u16*   xnbf = (u16*)alloc((size_t)kRows * kD * 2);
    u16*   h1bf = (u16*)alloc((size_t)kRows * kHmlp * 2);   // scratch region
    u16*   gbf  = (u16*)alloc((size_t)kRows * kHhalf * 2);
    // Aliased scratch (h1bf region is scratch-only now):
    //   Scf/Hinf (16MB each) during scan; Cp (4*2048*1024 f32 = 33.55MB)
    //   during G2 split-K and G4 split-K.
    float* Scf  = (float*)gbf;
    float* Hinf = (float*)h1bf;
    float* Cp   = (float*)h1bf;
    (void)ws_size; (void)in_sizes; (void)n_in; (void)out_size;

    // all casts in one dispatch (fc1 row-permuted for the gated epilogue)
    cast_all_kernel<<<kB5 / 256, 256, 0, stream>>>(
        x, in_proj_w, out_proj_w, fc1_w, fc2_w, xbf, w1bf, w2bf, w3bf, w4bf);

    // G1: zxbcdt = x @ in_proj^T   (2048 x 4352, bf16 out)
    gemm_bt<true><<<dim3(kDprojPad / 128, kRows / 128, 1), 256, 0, stream>>>(
        xbf, w1bf, zxbf, nullptr, kRows, kDprojPad, kD);

    // fused conv + dt
    convdt_kernel<<<dim3((kConvDim + kHeads + 255) / 256, kRows), 256, 0, stream>>>(
        zxbf, conv_w, conv_b, xsbf, BCf, dt_bias, A_log, dtf, dAf);

    // chunked scan
    scan_chunk_kernel<<<dim3(kNC, kHeads, 2), 256, 0, stream>>>(
        xsbf, BCf, dtf, dAf, Dvec, ysbf, Pf, Scf);
    chunk_state_kernel<<<64, 256, 0, stream>>>(Scf, Pf, Hinf);
    chunk_corr_kernel<<<dim3(kNC - 1, kHeads, 2), 256, 0, stream>>>(Hinf, BCf, Pf, ysbf);

    gatenorm_kernel<<<kRows, 256, 0, stream>>>(ysbf, zxbf, ssm_norm_w, ybf);

    // G2: x2 = y @ out_proj^T + x   (split-K=4 partials, then fused reduce+rms)
    gemm_bt<false><<<dim3(kD / 128, kRows / 128, 4), 256, 0, stream>>>(
        ybf, w2bf, Cp, nullptr, kRows, kD, kDinner);
    reduce_rms_kernel<<<kRows, 256, 0, stream>>>(Cp, x, x2, rms_w, xnbf);

    // G3+gate fused: g = a*silu(g') computed in-epilogue from permuted fc1
    gemm_bt<true, true><<<dim3(kHmlp / 128, kRows / 128, 1), 256, 0, stream>>>(
        xnbf, w3bf, gbf, nullptr, kRows, kHmlp, kD);

    // G4: out = g @ fc2^T + x2   (split-K=4 partials, then reduce+resid)
    gemm_bt<false><<<dim3(kD / 128, kRows / 128, 4), 256, 0, stream>>>(
        gbf, w4bf, Cp, nullptr, kRows, kD, kHhalf);
    splitk_reduce_kernel<<<(kRows * kD / 4 + 255) / 256, 256, 0, stream>>>(
        Cp, x2, out, kRows * kD / 4);
}

// Round 9
// 378.946 us; speedup vs baseline: 1.1512x; 1.1512x over previous
//
#include <hip/hip_runtime.h>
#include <math.h>

typedef unsigned short u16;
typedef __attribute__((ext_vector_type(8))) __bf16 bf16x8;
typedef __attribute__((ext_vector_type(4))) float f32x4;
typedef __attribute__((ext_vector_type(4))) u16 u16x4;
typedef __attribute__((ext_vector_type(8))) u16 u16x8;
typedef __attribute__((ext_vector_type(4))) float float4v;

constexpr int kS = 1024;
constexpr int kD = 1024;
constexpr int kDinner = 2048;
constexpr int kHeads = 32;
constexpr int kConvDim = 2176;
constexpr int kDproj = 4256;
constexpr int kDprojPad = 4352;
constexpr int kRows = 2048;   // B*S
constexpr int kHmlp = 8192;
constexpr int kHhalf = 4096;
constexpr int kL = 64;        // scan chunk length
constexpr int kNC = 16;       // chunks per sequence

__device__ __forceinline__ float bf2f(u16 u) {
    return __builtin_bit_cast(float, (unsigned int)u << 16);
}
__device__ __forceinline__ u16 f2bf(float f) {
    unsigned int u = __builtin_bit_cast(unsigned int, f);
    u += 0x7fffu + ((u >> 16) & 1u);
    return (u16)(u >> 16);
}
__device__ __forceinline__ float silu_(float x) { return x / (1.f + __expf(-x)); }

// async global->LDS, 16B per lane; LDS dest = wave-uniform base + lane*16
__device__ __forceinline__ void gld16(const u16* g, u16* l) {
    __builtin_amdgcn_global_load_lds(
        (const __attribute__((address_space(1))) void*)g,
        (__attribute__((address_space(3))) void*)l, 16, 0, 0);
}

// ---------------- fused casts: all 5 fp32->bf16 conversions in one launch ----
// fc1 is row-PERMUTED on cast so the MLP gate pair (a_p, g_p) lands in columns
// c and c+16 of the SAME lane's accumulator blocks:
//   a-row p      -> col (p>>4)*32 + (p&15)
//   g-row 4096+p -> col (p>>4)*32 + (p&15) + 16
constexpr int kB1 = kRows * kD / 4;                       // x
constexpr int kB2 = kB1 + kDprojPad * kD / 4;             // in_proj (padded)
constexpr int kB3 = kB2 + kD * kDinner / 4;               // out_proj
constexpr int kB4 = kB3 + kHmlp * kD / 4;                 // fc1 (permuted)
constexpr int kB5 = kB4 + kD * kHhalf / 4;                // fc2
__global__ __launch_bounds__(256)
void cast_all_kernel(const float* __restrict__ x, const float* __restrict__ w1,
                     const float* __restrict__ w2, const float* __restrict__ w3,
                     const float* __restrict__ w4, u16* __restrict__ xbf,
                     u16* __restrict__ w1bf, u16* __restrict__ w2bf,
                     u16* __restrict__ w3bf, u16* __restrict__ w4bf) {
    int i = blockIdx.x * 256 + threadIdx.x;
    const float* src;
    u16* dst;
    int j;
    if (i < kB1) {
        j = i; src = x; dst = xbf;
    } else if (i < kB2) {
        j = i - kB1;
        int e = j * 4, row = e >> 10, col = e & 1023;
        u16x4 o = {0, 0, 0, 0};
        if (row < kDproj) {
            float4v v = *(const float4v*)(w1 + (size_t)row * kD + col);
            o.x = f2bf(v.x); o.y = f2bf(v.y); o.z = f2bf(v.z); o.w = f2bf(v.w);
        }
        ((u16x4*)w1bf)[j] = o;
        return;
    } else if (i < kB3) {
        j = i - kB2; src = w2; dst = w2bf;
    } else if (i < kB4) {
        j = i - kB3;
        int e = j * 4, row = e >> 10, col4 = (e & 1023) >> 2;
        int p = (row < kHhalf) ? row : row - kHhalf;
        int permrow = (p >> 4) * 32 + (p & 15) + ((row < kHhalf) ? 0 : 16);
        float4v v = ((const float4v*)w3)[j];
        u16x4 o;
        o.x = f2bf(v.x); o.y = f2bf(v.y); o.z = f2bf(v.z); o.w = f2bf(v.w);
        ((u16x4*)w3bf)[permrow * 256 + col4] = o;
        return;
    } else {
        j = i - kB4; src = w4; dst = w4bf;
    }
    float4v v = ((const float4v*)src)[j];
    u16x4 o;
    o.x = f2bf(v.x); o.y = f2bf(v.y); o.z = f2bf(v.z); o.w = f2bf(v.w);
    ((u16x4*)dst)[j] = o;
}

// ---------------- GEMM: C[M,N] = A[M,K] * W[N,K]^T ----------------
// m97 staging (R6 layout: lane>>2 rows — global-coalesced; the resulting
// 8-way LDS read conflict measured CHEAPER than de-conflicted-but-scattered
// staging, R7) + double-buffered LDS, one barrier per K-iter.
// blockIdx.z = split-K slice (partials at Cout + z*M*N, fp32, no resid).
// GATED: W is the permuted fc1; gate pair sits in ni blocks (2p, 2p+1) of the
// same lane -> epilogue computes a*silu(g) with no shuffle, all lanes store.
template <bool OUT_BF16, bool GATED = false>
__global__ __launch_bounds__(256)
void gemm_bt(const u16* __restrict__ A, const u16* __restrict__ W,
             void* __restrict__ Cout, const float* __restrict__ resid,
             int M, int N, int K) {
    __shared__ u16 As[2][128 * 32];
    __shared__ u16 Bs[2][128 * 32];
    const int tid = threadIdx.x;
    const int lane = tid & 63;
    const int w = __builtin_amdgcn_readfirstlane(tid >> 6);
    const int wm = w >> 1, wn = w & 1;
    const int bm = blockIdx.y * 128;
    const int bn = blockIdx.x * 128;
    const int z = blockIdx.z;
    const int Kchunk = K / gridDim.z;
    const int k0 = z * Kchunk;

    f32x4 acc[4][4];
#pragma unroll
    for (int i = 0; i < 4; i++)
#pragma unroll
        for (int j = 0; j < 4; j++) acc[i][j] = {0.f, 0.f, 0.f, 0.f};

    // staging: lane -> (row = lane>>2, kchunk = lane&3): global-coalesced
    const int srow = lane >> 2;          // 0..15
    const int scol = (lane & 3) * 8;     // k elem
    const u16* gA = A + (size_t)(bm + w * 32 + srow) * K + k0 + scol;
    const u16* gB = W + (size_t)(bn + w * 32 + srow) * K + k0 + scol;
    const size_t rstep = (size_t)16 * K;

    const int sbase0 = (w * 32) * 32;
    const int sbase1 = (w * 32 + 16) * 32;
    const int fra = (lane & 15) * 32 + (lane >> 4) * 8;

    // prologue: stage tile 0 into buffer 0
    gld16(gA, &As[0][sbase0]);
    gld16(gA + rstep, &As[0][sbase1]);
    gld16(gB, &Bs[0][sbase0]);
    gld16(gB + rstep, &Bs[0][sbase1]);

    const int nk = Kchunk >> 5;
    for (int i = 0; i < nk; i++) {
        const int cur = i & 1, nxt = cur ^ 1;
        __syncthreads();   // drains DMA for buf[cur]; buf[nxt] reads finished
        if (i + 1 < nk) {
            int kt2 = (i + 1) * 32;
            gld16(gA + kt2, &As[nxt][sbase0]);
            gld16(gA + kt2 + rstep, &As[nxt][sbase1]);
            gld16(gB + kt2, &Bs[nxt][sbase0]);
            gld16(gB + kt2 + rstep, &Bs[nxt][sbase1]);
        }
        bf16x8 av[4], bv[4];
#pragma unroll
        for (int mi = 0; mi < 4; mi++)
            av[mi] = *(const bf16x8*)&As[cur][(wm * 64 + mi * 16) * 32 + fra];
#pragma unroll
        for (int ni = 0; ni < 4; ni++)
            bv[ni] = *(const bf16x8*)&Bs[cur][(wn * 64 + ni * 16) * 32 + fra];
#pragma unroll
        for (int mi = 0; mi < 4; mi++)
#pragma unroll
            for (int ni = 0; ni < 4; ni++)
                acc[mi][ni] = __builtin_amdgcn_mfma_f32_16x16x32_bf16(av[mi], bv[ni], acc[mi][ni], 0, 0, 0);
    }

    const int rb = bm + wm * 64 + ((lane >> 4) << 2);
    const int cb = bn + wn * 64 + (lane & 15);
    if (GATED) {
        // ni pair (2p, 2p+1): a in block 2p, g in block 2p+1, same lane.
        // gate-col = (bn + wn*64)/2 + p*16 + (lane&15)
        u16* Cb = (u16*)Cout;
        const int NG = N >> 1;
        const int gc0 = ((bn + wn * 64) >> 1) + (lane & 15);
#pragma unroll
        for (int mi = 0; mi < 4; mi++) {
#pragma unroll
            for (int p = 0; p < 2; p++) {
#pragma unroll
                for (int r = 0; r < 4; r++) {
                    float a = acc[mi][2 * p][r];
                    float g = acc[mi][2 * p + 1][r];
                    Cb[(size_t)(rb + mi * 16 + r) * NG + gc0 + p * 16] =
                        f2bf(a * silu_(g));
                }
            }
        }
        return;
    }
    float* Cf = (float*)Cout + (size_t)z * M * N;
    u16* Cb = (u16*)Cout;
#pragma unroll
    for (int mi = 0; mi < 4; mi++) {
#pragma unroll
        for (int ni = 0; ni < 4; ni++) {
#pragma unroll
            for (int r = 0; r < 4; r++) {
                size_t offo = (size_t)(rb + mi * 16 + r) * N + (cb + ni * 16);
                float v = acc[mi][ni][r];
                if (resid) v += resid[offo];
                if (OUT_BF16) Cb[offo] = f2bf(v);
                else Cf[offo] = v;
            }
        }
    }
}

// ---------------- split-K reduce (SK=4) + residual, fp32 out ----------------
__global__ __launch_bounds__(256)
void splitk_reduce_kernel(const float* __restrict__ Cp, const float* __restrict__ resid,
                          float* __restrict__ out, int mn4) {
    int i = blockIdx.x * 256 + threadIdx.x;
    if (i >= mn4) return;
    constexpr size_t MN = (size_t)kRows * kD;
    float4v s0 = ((const float4v*)Cp)[i];
    float4v s1 = ((const float4v*)(Cp + MN))[i];
    float4v s2 = ((const float4v*)(Cp + 2 * MN))[i];
    float4v s3 = ((const float4v*)(Cp + 3 * MN))[i];
    float4v r = ((const float4v*)resid)[i];
    float4v o;
    o.x = s0.x + s1.x + s2.x + s3.x + r.x;
    o.y = s0.y + s1.y + s2.y + s3.y + r.y;
    o.z = s0.z + s1.z + s2.z + s3.z + r.z;
    o.w = s0.w + s1.w + s2.w + s3.w + r.w;
    ((float4v*)out)[i] = o;
}

// ------- fused: split-K reduce + residual + RMSNorm(1024) -> x2 fp32, xn bf16
__global__ __launch_bounds__(256)
void reduce_rms_kernel(const float* __restrict__ Cp, const float* __restrict__ resid,
                       float* __restrict__ x2, const float* __restrict__ rmsw,
                       u16* __restrict__ xnbf) {
    const int row = blockIdx.x;
    const int tid = threadIdx.x;
    constexpr size_t MN = (size_t)kRows * kD;
    size_t i = (size_t)row * (kD / 4) + tid;
    float4v s0 = ((const float4v*)Cp)[i];
    float4v s1 = ((const float4v*)(Cp + MN))[i];
    float4v s2 = ((const float4v*)(Cp + 2 * MN))[i];
    float4v s3 = ((const float4v*)(Cp + 3 * MN))[i];
    float4v r = ((const float4v*)resid)[i];
    float4v v;
    v.x = s0.x + s1.x + s2.x + s3.x + r.x;
    v.y = s0.y + s1.y + s2.y + s3.y + r.y;
    v.z = s0.z + s1.z + s2.z + s3.z + r.z;
    v.w = s0.w + s1.w + s2.w + s3.w + r.w;
    ((float4v*)x2)[i] = v;
    float ss = v.x * v.x + v.y * v.y + v.z * v.z + v.w * v.w;
#pragma unroll
    for (int off = 32; off > 0; off >>= 1) ss += __shfl_down(ss, off);
    __shared__ float red[4];
    int wv = tid >> 6, lane = tid & 63;
    if (lane == 0) red[wv] = ss;
    __syncthreads();
    ss = red[0] + red[1] + red[2] + red[3];
    float rstd = rsqrtf(ss * (1.f / kD) + 1e-5f);
    float4v wv4 = ((const float4v*)rmsw)[tid];
    u16x4 o;
    o.x = f2bf(v.x * rstd * wv4.x);
    o.y = f2bf(v.y * rstd * wv4.y);
    o.z = f2bf(v.z * rstd * wv4.z);
    o.w = f2bf(v.w * rstd * wv4.w);
    ((u16x4*)xnbf)[i] = o;
}

// ---------------- fused depthwise causal conv + silu + dt/dA ----------------
__global__ __launch_bounds__(256)
void convdt_kernel(const u16* __restrict__ zxbf, const float* __restrict__ convw,
                   const float* __restrict__ convb, u16* __restrict__ xsbf,
                   float* __restrict__ BCf, const float* __restrict__ dt_bias,
                   const float* __restrict__ A_log, float* __restrict__ dtf,
                   float* __restrict__ dAf) {
    int c = blockIdx.x * 256 + threadIdx.x;
    int row = blockIdx.y;                 // b*1024 + s
    if (c >= kConvDim + kHeads) return;
    if (c < kConvDim) {
        int s = row & (kS - 1);
        float acc = convb[c];
#pragma unroll
        for (int j = 0; j < 4; j++) {
            int sj = s - 3 + j;
            if (sj >= 0)
                acc += bf2f(zxbf[(size_t)(row - 3 + j) * kDprojPad + kDinner + c]) * convw[c * 4 + j];
        }
        float v = silu_(acc);
        if (c < kDinner) xsbf[(size_t)row * kDinner + c] = f2bf(v);
        else BCf[(size_t)row * 128 + (c - kDinner)] = v;
    } else {
        int h = c - kConvDim;
        float raw = bf2f(zxbf[(size_t)row * kDprojPad + (kDinner + kConvDim) + h]) + dt_bias[h];
        float dt = (raw > 20.f) ? raw : log1pf(__expf(raw));
        float dA = __expf(-dt * __expf(A_log[h]));
        dtf[(size_t)row * kHeads + h] = dt;
        dAf[(size_t)row * kHeads + h] = dA;
    }
}

// ---------------- Phase A: intra-chunk local scan ----------------
__global__ __launch_bounds__(256)
void scan_chunk_kernel(const u16* __restrict__ xsbf, const float* __restrict__ BCf,
                       const float* __restrict__ dtf, const float* __restrict__ dAf,
                       const float* __restrict__ Dv, u16* __restrict__ ysbf,
                       float* __restrict__ Pf, float* __restrict__ Scf) {
    const int c = blockIdx.x, h = blockIdx.y, b = blockIdx.z;
    const int tid = threadIdx.x;
    const int lane = tid & 63;
    const int nq = tid >> 6;
    const int p = nq * 16 + (lane & 15);
    const int ng = lane >> 4;

    __shared__ float BC_lds[kL * 136];   // B at t*136+n, C at t*136+68+n
    __shared__ u16 xs_lds[kL * 64];
    __shared__ float dA_lds[kL];
    __shared__ float dt_lds[kL];
    __shared__ u16 ybuf[kL * 64];

    const int row0 = b * kS + c * kL;

#pragma unroll
    for (int i = 0; i < 8; i++) {
        int e4 = i * 256 + tid;
        int t = e4 >> 5;
        int col = (e4 & 31) * 4;
        float4v v = *(const float4v*)(BCf + (size_t)(row0 + t) * 128 + col);
        int dst = t * 136 + (col < 64 ? col : col + 4);
        *(float4v*)&BC_lds[dst] = v;
    }
#pragma unroll
    for (int i = 0; i < 2; i++) {
        int e8 = i * 256 + tid;
        int t = e8 >> 3, col8 = (e8 & 7) * 8;
        *(u16x8*)&xs_lds[t * 64 + col8] =
            *(const u16x8*)(xsbf + (size_t)(row0 + t) * kDinner + h * 64 + col8);
    }
    if (tid < kL) {
        dt_lds[tid] = dtf[(size_t)(row0 + tid) * kHeads + h];
        dA_lds[tid] = dAf[(size_t)(row0 + tid) * kHeads + h];
    }
    __syncthreads();

    float hst[16];
#pragma unroll
    for (int j = 0; j < 16; j++) hst[j] = 0.f;
    float P = 1.f;
    const float Dh = Dv[h];

    for (int t = 0; t < kL; t++) {
        float dAv = dA_lds[t];
        float dtv = dt_lds[t];
        float xsv = bf2f(xs_lds[t * 64 + p]);
        float dtx = dtv * xsv;
        P *= dAv;
        const float* Bt = &BC_lds[t * 136 + ng * 16];
        const float* Ct = Bt + 68;
        float yp = 0.f;
#pragma unroll
        for (int j = 0; j < 16; j++) {
            float Bn = Bt[j];
            float Cn = Ct[j];
            hst[j] = hst[j] * dAv + dtx * Bn;
            yp += hst[j] * Cn;
        }
        yp += __shfl_xor(yp, 16);
        yp += __shfl_xor(yp, 32);
        if (ng == 0) ybuf[t * 64 + p] = f2bf(yp + Dh * xsv);
        if (tid == 0) Pf[(size_t)(row0 + t) * kHeads + h] = P;
    }
    __syncthreads();

#pragma unroll
    for (int i = 0; i < 2; i++) {
        int e8 = i * 256 + tid;
        int t = e8 >> 3, col8 = (e8 & 7) * 8;
        *(u16x8*)(ysbf + (size_t)(row0 + t) * kDinner + h * 64 + col8) =
            *(u16x8*)&ybuf[t * 64 + col8];
    }
    const int bhc = (b * 32 + h) * kNC + c;
    float* Sdst = Scf + (size_t)bhc * 4096 + p * 64 + ng * 16;
#pragma unroll
    for (int j = 0; j < 16; j += 4) {
        f32x4 v = {hst[j], hst[j + 1], hst[j + 2], hst[j + 3]};
        *(f32x4*)(Sdst + j) = v;
    }
}

// ---------------- Phase B: sequential chunk-state combine ----------------
__global__ __launch_bounds__(256)
void chunk_state_kernel(const float* __restrict__ Scf, const float* __restrict__ Pf,
                        float* __restrict__ Hinf) {
    const int bh = blockIdx.x;
    const int b = bh >> 5, h = bh & 31;
    const int tid = threadIdx.x;
    float hreg[16];
#pragma unroll
    for (int k = 0; k < 16; k++) hreg[k] = 0.f;
    for (int c = 0; c < kNC - 1; c++) {
        float Q = Pf[(size_t)(b * kS + c * kL + kL - 1) * kHeads + h];
        size_t sbase = (size_t)(bh * kNC + c) * 4096;
        size_t dbase = (size_t)(bh * kNC + c + 1) * 4096;
#pragma unroll
        for (int k = 0; k < 16; k++) {
            float s = Scf[sbase + k * 256 + tid];
            hreg[k] = Q * hreg[k] + s;
            Hinf[dbase + k * 256 + tid] = hreg[k];
        }
    }
}

// ---------------- Phase C: cross-chunk correction ----------------
__global__ __launch_bounds__(256)
void chunk_corr_kernel(const float* __restrict__ Hinf, const float* __restrict__ BCf,
                       const float* __restrict__ Pf, u16* __restrict__ ysbf) {
    const int c = blockIdx.x + 1;
    const int h = blockIdx.y, b = blockIdx.z;
    const int tid = threadIdx.x;
    const int lane = tid & 63, wq = tid >> 6;
    __shared__ float Hin_lds[64 * 65];
    __shared__ float C_lds[kL * 64];
    const int bh = b * 32 + h;
    const size_t hbase = (size_t)(bh * kNC + c) * 4096;
#pragma unroll
    for (int k = 0; k < 16; k++) {
        int e = k * 256 + tid;
        Hin_lds[(e >> 6) * 65 + (e & 63)] = Hinf[hbase + e];
    }
    const int row0 = b * kS + c * kL;
#pragma unroll
    for (int k = 0; k < 4; k++) {
        int e4 = k * 256 + tid;
        int t = e4 >> 4, n4 = (e4 & 15) * 4;
        *(float4v*)&C_lds[t * 64 + n4] =
            *(const float4v*)(BCf + (size_t)(row0 + t) * 128 + 64 + n4);
    }
    __syncthreads();

    float hr[64];
#pragma unroll
    for (int n = 0; n < 64; n++) hr[n] = Hin_lds[lane * 65 + n];

    for (int tt = 0; tt < 16; tt++) {
        int t = wq * 16 + tt;
        float corr = 0.f;
#pragma unroll
        for (int n4 = 0; n4 < 16; n4++) {
            float4v cv = *(const float4v*)&C_lds[t * 64 + n4 * 4];
            corr += cv.x * hr[n4 * 4] + cv.y * hr[n4 * 4 + 1] +
                    cv.z * hr[n4 * 4 + 2] + cv.w * hr[n4 * 4 + 3];
        }
        float Pt = Pf[(size_t)(row0 + t) * kHeads + h];
        size_t yoff = (size_t)(row0 + t) * kDinner + h * 64 + lane;
        ysbf[yoff] = f2bf(bf2f(ysbf[yoff]) + Pt * corr);
    }
}

// ---------------- gate (silu(z)) + rmsnorm over 2048 ----------------
__global__ __launch_bounds__(256)
void gatenorm_kernel(const u16* __restrict__ ysbf, const u16* __restrict__ zxbf,
                     const float* __restrict__ normw, u16* __restrict__ ybf) {
    const int row = blockIdx.x;
    const int tid = threadIdx.x;
    float v[8];
    float ss = 0.f;
#pragma unroll
    for (int i = 0; i < 8; i++) {
        int idx = i * 256 + tid;
        float y = bf2f(ysbf[(size_t)row * kDinner + idx]);
        float z = bf2f(zxbf[(size_t)row * kDprojPad + idx]);
        v[i] = y * silu_(z);
        ss += v[i] * v[i];
    }
#pragma unroll
    for (int off = 32; off > 0; off >>= 1) ss += __shfl_down(ss, off);
    __shared__ float red[4];
    int wv = tid >> 6, lane = tid & 63;
    if (lane == 0) red[wv] = ss;
    __syncthreads();
    ss = red[0] + red[1] + red[2] + red[3];
    float rstd = rsqrtf(ss * (1.f / kDinner) + 1e-5f);
#pragma unroll
    for (int i = 0; i < 8; i++) {
        int idx = i * 256 + tid;
        ybf[(size_t)row * kDinner + idx] = f2bf(v[i] * rstd * normw[idx]);
    }
}

extern "C" void kernel_launch(void* const* d_in, const int* in_sizes, int n_in,
                              void* d_out, int out_size, void* d_ws, size_t ws_size,
                              hipStream_t stream) {
    const float* x         = (const float*)d_in[0];
    const float* in_proj_w = (const float*)d_in[1];
    const float* conv_w    = (const float*)d_in[2];
    const float* conv_b    = (const float*)d_in[3];
    const float* dt_bias   = (const float*)d_in[4];
    const float* A_log     = (const float*)d_in[5];
    const float* Dvec      = (const float*)d_in[6];
    const float* ssm_norm_w= (const float*)d_in[7];
    const float* out_proj_w= (const float*)d_in[8];
    const float* rms_w     = (const float*)d_in[9];
    const float* fc1_w     = (const float*)d_in[10];
    const float* fc2_w     = (const float*)d_in[11];
    float* out = (float*)d_out;

    char* ws = (char*)d_ws;
    size_t off = 0;
    auto alloc = [&](size_t bytes) -> void* {
        void* p = ws + off;
        off += (bytes + 255) & ~(size_t)255;
        return p;
    };
    u16*   xbf  = (u16*)alloc((size_t)kRows * kD * 2);
    u16*   w1bf = (u16*)alloc((size_t)kDprojPad * kD * 2);
    u16*   w2bf = (u16*)alloc((size_t)kD * kDinner * 2);
    u16*   w3bf = (u16*)alloc((size_t)kHmlp * kD * 2);
    u16*   w4bf = (u16*)alloc((size_t)kD * kHhalf * 2);
    u16*   zxbf = (u16*)alloc((size_t)kRows * kDprojPad * 2);
    u16*   xsbf = (u16*)alloc((size_t)kRows * kDinner * 2);
    float* BCf  = (float*)alloc((size_t)kRows * 128 * 4);
    float* dtf  = (float*)alloc((size_t)kRows * kHeads * 4);
    float* dAf  = (float*)alloc((size_t)kRows * kHeads * 4);
    float* Pf   = (float*)alloc((size_t)kRows * kHeads * 4);
    u16*   ysbf = (u16*)alloc((size_t)kRows * kDinner * 2);
    u16*   ybf  = (u16*)alloc((size_t)kRows * kDinner * 2);
    float* x2   = (float*)alloc((size_t)kRows * kD * 4);
    u16*   xnbf = (u16*)alloc((size_t)kRows * kD * 2);
    u16*   h1bf = (u16*)alloc((size_t)kRows * kHmlp * 2);   // scratch region
    u16*   gbf  = (u16*)alloc((size_t)kRows * kHhalf * 2);
    // Aliased scratch (h1bf region is scratch-only now):
    //   Scf/Hinf (16MB each) during scan; Cp (4*2048*1024 f32 = 33.55MB)
    //   during G2 split-K and G4 split-K.
    float* Scf  = (float*)gbf;
    float* Hinf = (float*)h1bf;
    float* Cp   = (float*)h1bf;
    (void)ws_size; (void)in_sizes; (void)n_in; (void)out_size;

    // all casts in one dispatch (fc1 row-permuted for the gated epilogue)
    cast_all_kernel<<<kB5 / 256, 256, 0, stream>>>(
        x, in_proj_w, out_proj_w, fc1_w, fc2_w, xbf, w1bf, w2bf, w3bf, w4bf);

    // G1: zxbcdt = x @ in_proj^T   (2048 x 4352, bf16 out)
    gemm_bt<true><<<dim3(kDprojPad / 128, kRows / 128, 1), 256, 0, stream>>>(
        xbf, w1bf, zxbf, nullptr, kRows, kDprojPad, kD);

    // fused conv + dt
    convdt_kernel<<<dim3((kConvDim + kHeads + 255) / 256, kRows), 256, 0, stream>>>(
        zxbf, conv_w, conv_b, xsbf, BCf, dt_bias, A_log, dtf, dAf);

    // chunked scan
    scan_chunk_kernel<<<dim3(kNC, kHeads, 2), 256, 0, stream>>>(
        xsbf, BCf, dtf, dAf, Dvec, ysbf, Pf, Scf);
    chunk_state_kernel<<<64, 256, 0, stream>>>(Scf, Pf, Hinf);
    chunk_corr_kernel<<<dim3(kNC - 1, kHeads, 2), 256, 0, stream>>>(Hinf, BCf, Pf, ysbf);

    gatenorm_kernel<<<kRows, 256, 0, stream>>>(ysbf, zxbf, ssm_norm_w, ybf);

    // G2: x2 = y @ out_proj^T + x   (split-K=4 partials, then fused reduce+rms)
    gemm_bt<false><<<dim3(kD / 128, kRows / 128, 4), 256, 0, stream>>>(
        ybf, w2bf, Cp, nullptr, kRows, kD, kDinner);
    reduce_rms_kernel<<<kRows, 256, 0, stream>>>(Cp, x, x2, rms_w, xnbf);

    // G3+gate fused: g = a*silu(g') computed in-epilogue from permuted fc1
    gemm_bt<true, true><<<dim3(kHmlp / 128, kRows / 128, 1), 256, 0, stream>>>(
        xnbf, w3bf, gbf, nullptr, kRows, kHmlp, kD);

    // G4: out = g @ fc2^T + x2   (split-K=4 partials, then reduce+resid)
    gemm_bt<false><<<dim3(kD / 128, kRows / 128, 4), 256, 0, stream>>>(
        gbf, w4bf, Cp, nullptr, kRows, kD, kHhalf);
    splitk_reduce_kernel<<<(kRows * kD / 4 + 255) / 256, 256, 0, stream>>>(
        Cp, x2, out, kRows * kD / 4);
}